// Round 5
// baseline (408.100 us; speedup 1.0000x reference)
//
#include <hip/hip_runtime.h>
#include <hip/hip_bf16.h>

#define NH 16
#define DH 64
#define DMODEL 1024
#define CL 16
#define SEQL 2048
#define NBATCH 2
#define G 32            // NBATCH*NH
#define TS 64           // s-tile size
#define NTILE (SEQL/TS) // 32

typedef float f32x4 __attribute__((ext_vector_type(4)));
typedef short bf16x8 __attribute__((ext_vector_type(8)));

#define FMA16(acc, a, b) do { \
  acc[0][0] += (a).x*(b).x; acc[0][1] += (a).x*(b).y; acc[0][2] += (a).x*(b).z; acc[0][3] += (a).x*(b).w; \
  acc[1][0] += (a).y*(b).x; acc[1][1] += (a).y*(b).y; acc[1][2] += (a).y*(b).z; acc[1][3] += (a).y*(b).w; \
  acc[2][0] += (a).z*(b).x; acc[2][1] += (a).z*(b).y; acc[2][2] += (a).z*(b).z; acc[2][3] += (a).z*(b).w; \
  acc[3][0] += (a).w*(b).x; acc[3][1] += (a).w*(b).y; acc[3][2] += (a).w*(b).z; acc[3][3] += (a).w*(b).w; \
} while(0)

// ---------------------------------------------------------------------------
// bf16-split MFMA GEMM core: C(128x128) = A @ W^T, A,W row-major fp32, K=1024.
// a = hi + lo (bf16 truncation split; bf16 exponent range == fp32, so NO
// subnormal hazard at any operand scale). D = ah*bh + ah*bl + al*bh (3 MFMA);
// dropped al*bl + residual ~2^-16 relative per product (~1.5e-5 end-to-end).
// LDS rows: 64 shorts = 128B = 8x16B slots, swizzled slot^=(row&7): both
// ds_write_b128 staging and ds_read_b128 frag reads hit each 4-bank group
// exactly 8x per wave -> conflict-free (hand-enumerated).
// Frag map (m89/m97-verified): lane l: row=l&15, k=(l>>4)*8+0..7 contiguous
// (any k-group permutation error cancels: A/B use identical k-maps and MFMA
// pairs operands symmetrically). C/D: col(n)=l&15, row(m)=(l>>4)*4+reg.
// ---------------------------------------------------------------------------
__device__ __forceinline__ int swz(int row, int slot) {
  // offset in shorts; slot is a 16B (8-short) unit, 8 slots per 128B row
  return row * 64 + ((slot ^ (row & 7)) << 3);
}

// stages 16 fp32 (one row, 16 k) as hi/lo bf16 into LDS with swizzle
__device__ __forceinline__ void stage16(short* L, const float* src, int row, int h2) {
  float f[16];
  *(float4*)&f[0]  = *(const float4*)(src + 0);
  *(float4*)&f[4]  = *(const float4*)(src + 4);
  *(float4*)&f[8]  = *(const float4*)(src + 8);
  *(float4*)&f[12] = *(const float4*)(src + 12);
  bf16x8 hi0, hi1, lo0, lo1;
#pragma unroll
  for (int j = 0; j < 8; ++j) {
    const unsigned bits = __float_as_uint(f[j]);
    hi0[j] = (short)(bits >> 16);
    const float lof = f[j] - __uint_as_float(bits & 0xFFFF0000u); // exact
    lo0[j] = (short)(__float_as_uint(lof) >> 16);
  }
#pragma unroll
  for (int j = 0; j < 8; ++j) {
    const unsigned bits = __float_as_uint(f[8 + j]);
    hi1[j] = (short)(bits >> 16);
    const float lof = f[8 + j] - __uint_as_float(bits & 0xFFFF0000u);
    lo1[j] = (short)(__float_as_uint(lof) >> 16);
  }
  *(bf16x8*)&L[swz(row, h2 * 2 + 0)] = hi0;
  *(bf16x8*)&L[swz(row, h2 * 2 + 1)] = hi1;
  *(bf16x8*)&L[swz(row, 4 + h2 * 2 + 0)] = lo0;
  *(bf16x8*)&L[swz(row, 4 + h2 * 2 + 1)] = lo1;
}

#define GEMM_CORE(Aglob, Wglob)                                              \
  __shared__ short LA[128 * 64];                                             \
  __shared__ short LB[128 * 64];                                             \
  const int tid = threadIdx.x;                                               \
  const int m0 = blockIdx.x * 128, n0 = blockIdx.y * 128;                    \
  const int srow = tid >> 1;       /* staging row 0..127 */                  \
  const int h2 = tid & 1;          /* staging k-half */                      \
  const int wv = tid >> 6;                                                   \
  const int wr = wv >> 1, wc = wv & 1;                                       \
  const int lane = tid & 63;                                                 \
  const int lr = lane & 15, kg = lane >> 4;                                  \
  f32x4 acc[4][4] = {};                                                      \
  const float* Ap = Aglob + (size_t)(m0 + srow) * DMODEL + h2 * 16;          \
  const float* Bp = Wglob + (size_t)(n0 + srow) * DMODEL + h2 * 16;          \
  int offAh[4], offAl[4], offBh[4], offBl[4];                                \
  _Pragma("unroll")                                                          \
  for (int t = 0; t < 4; ++t) {                                              \
    const int ra = wr * 64 + t * 16 + lr;                                    \
    const int rb = wc * 64 + t * 16 + lr;                                    \
    offAh[t] = swz(ra, kg);     offAl[t] = swz(ra, 4 + kg);                  \
    offBh[t] = swz(rb, kg);     offBl[t] = swz(rb, 4 + kg);                  \
  }                                                                          \
  for (int k0 = 0; k0 < DMODEL; k0 += 32) {                                  \
    __syncthreads(); /* prev compute done reading LDS */                     \
    stage16(LA, Ap + k0, srow, h2);                                          \
    stage16(LB, Bp + k0, srow, h2);                                          \
    __syncthreads(); /* tiles ready */                                       \
    bf16x8 ah[4], al[4], bh[4], bl[4];                                       \
    _Pragma("unroll")                                                        \
    for (int t = 0; t < 4; ++t) {                                            \
      ah[t] = *(const bf16x8*)&LA[offAh[t]];                                 \
      al[t] = *(const bf16x8*)&LA[offAl[t]];                                 \
      bh[t] = *(const bf16x8*)&LB[offBh[t]];                                 \
      bl[t] = *(const bf16x8*)&LB[offBl[t]];                                 \
    }                                                                        \
    _Pragma("unroll")                                                        \
    for (int mt = 0; mt < 4; ++mt) {                                         \
      _Pragma("unroll")                                                      \
      for (int nt = 0; nt < 4; ++nt) {                                       \
        acc[mt][nt] = __builtin_amdgcn_mfma_f32_16x16x32_bf16(               \
            ah[mt], bh[nt], acc[mt][nt], 0, 0, 0);                           \
        acc[mt][nt] = __builtin_amdgcn_mfma_f32_16x16x32_bf16(               \
            ah[mt], bl[nt], acc[mt][nt], 0, 0, 0);                           \
        acc[mt][nt] = __builtin_amdgcn_mfma_f32_16x16x32_bf16(               \
            al[mt], bh[nt], acc[mt][nt], 0, 0, 0);                           \
      }                                                                      \
    }                                                                        \
  }

// ---------------------------------------------------------------------------
// QKV projection (MFMA): z picks q/k/v; scatter to [g=b*16+h][s][d], q scaled
// by 1/(8*exp(beta[h])).
// ---------------------------------------------------------------------------
__global__ __launch_bounds__(256) void proj_qkv(
    const float* __restrict__ x,
    const float* __restrict__ Wq, const float* __restrict__ bq,
    const float* __restrict__ Wk, const float* __restrict__ bk,
    const float* __restrict__ Wv, const float* __restrict__ bv,
    const float* __restrict__ beta,
    float* __restrict__ qd, float* __restrict__ kd, float* __restrict__ vd)
{
  const int z = blockIdx.z;
  const float* W; const float* bias; float* dst;
  if (z == 0)      { W = Wq; bias = bq; dst = qd; }
  else if (z == 1) { W = Wk; bias = bk; dst = kd; }
  else             { W = Wv; bias = bv; dst = vd; }

  GEMM_CORE(x, W)

#pragma unroll
  for (int mt = 0; mt < 4; ++mt) {
    const int mb = m0 + wr * 64 + mt * 16 + (lane >> 4) * 4;
#pragma unroll
    for (int nt = 0; nt < 4; ++nt) {
      const int n = n0 + wc * 64 + nt * 16 + (lane & 15);
      const int h = n >> 6, d0m = n & 63;
      const float scale = (z == 0) ? (1.0f / (8.0f * __expf(beta[h]))) : 1.0f;
      const float bb = bias[n];
      const f32x4 a = acc[mt][nt];
#pragma unroll
      for (int j = 0; j < 4; ++j) {
        const int m = mb + j;
        const int s = m >> 1, b = m & 1;
        dst[((size_t)(b * NH + h) * SEQL + s) * DH + d0m] = (a[j] + bb) * scale;
      }
    }
  }
}

// ---------------------------------------------------------------------------
// Final projection (MFMA): out = od(4096x1024) @ Wo^T + bo, row-major.
// ---------------------------------------------------------------------------
__global__ __launch_bounds__(256) void gemm_out(
    const float* __restrict__ A, const float* __restrict__ W,
    const float* __restrict__ bias, float* __restrict__ C)
{
  GEMM_CORE(A, W)

#pragma unroll
  for (int mt = 0; mt < 4; ++mt) {
    const int mb = m0 + wr * 64 + mt * 16 + (lane >> 4) * 4;
#pragma unroll
    for (int nt = 0; nt < 4; ++nt) {
      const int n = n0 + wc * 64 + nt * 16 + (lane & 15);
      const float bb = bias[n];
      const f32x4 a = acc[mt][nt];
#pragma unroll
      for (int j = 0; j < 4; ++j)
        C[(size_t)(mb + j) * DMODEL + n] = a[j] + bb;
    }
  }
}

// ---------------------------------------------------------------------------
// Pass A: per (g, tile) block sums: bsnum[g][nb][c][e] = sum_t w[c,t]*kv[t,e],
// bsden[g][nb][c] = sum_t w[c,t], with w = exp(qc . k) (max-shift dropped:
// logits are O(1) (std~0.25), and num/den is shift-invariant).
// ---------------------------------------------------------------------------
__global__ __launch_bounds__(256) void passA(
    const float* __restrict__ kd, const float* __restrict__ vd,
    const float* __restrict__ q_c,
    float* __restrict__ bsden, float* __restrict__ bsnum)
{
  const int g = blockIdx.x, nb = blockIdx.y, h = g & (NH-1);
  const int s0 = nb * TS;
  __shared__ float Ks[TS][68];
  __shared__ float Vs[TS][68];
  __shared__ float qc[CL][68];
  __shared__ float Wm[TS][17];
  const int tid = threadIdx.x;

  {
    const int c = tid >> 4, d4 = (tid & 15) * 4;
    *(float4*)&qc[c][d4] = *(const float4*)&q_c[c*DMODEL + h*DH + d4];
  }
#pragma unroll
  for (int it = 0; it < 4; ++it) {
    const int r = (tid >> 4) + it*16, d4 = (tid & 15) * 4;
    *(float4*)&Ks[r][d4] = *(const float4*)&kd[((size_t)g*SEQL + s0 + r)*DH + d4];
    *(float4*)&Vs[r][d4] = *(const float4*)&vd[((size_t)g*SEQL + s0 + r)*DH + d4];
  }
  __syncthreads();

#pragma unroll
  for (int it = 0; it < 4; ++it) {
    const int item = tid + it*256;
    const int t = item & 63, c = item >> 6;
    float dot = 0.f;
    for (int d = 0; d < DH; ++d) dot += qc[c][d] * Ks[t][d];
    Wm[t][c] = __expf(dot);
  }
  __syncthreads();

  const size_t base = ((size_t)g*NTILE + nb) * CL;
#pragma unroll
  for (int it = 0; it < 8; ++it) {
    const int item = tid + it*256;
    const int e = item & 127, c = item >> 7;
    float sum = 0.f;
    if (e < 64) { for (int t = 0; t < TS; ++t) sum += Wm[t][c] * Ks[t][e]; }
    else        { const int e2 = e - 64;
                  for (int t = 0; t < TS; ++t) sum += Wm[t][c] * Vs[t][e2]; }
    bsnum[(base + c)*128 + e] = sum;
  }
  if (tid < CL) {
    float s = 0.f;
    for (int t = 0; t < TS; ++t) s += Wm[t][tid];
    bsden[base + tid] = s;
  }
}

// ---------------------------------------------------------------------------
// Pass B: in-place exclusive prefix over the NTILE tiles, per (g,c,element).
// ---------------------------------------------------------------------------
__global__ __launch_bounds__(256) void passB(
    float* __restrict__ bsden, float* __restrict__ bsnum)
{
  const int t = blockIdx.x * 256 + threadIdx.x;
  if (t >= G*CL*129) return;
  const int g = t / (CL*129);
  const int r = t % (CL*129);
  const int c = r / 129;
  const int e = r % 129;
  float run = 0.f;
  if (e == 128) {
    for (int i = 0; i < NTILE; ++i) {
      const size_t a = ((size_t)g*NTILE + i)*CL + c;
      const float x = bsden[a]; bsden[a] = run; run += x;
    }
  } else {
    for (int i = 0; i < NTILE; ++i) {
      const size_t a = (((size_t)g*NTILE + i)*CL + c)*128 + e;
      const float x = bsnum[a]; bsnum[a] = run; run += x;
    }
  }
}

// ---------------------------------------------------------------------------
// Pass C: per (g, s-tile): recompute Wm, den prefix, A = tril(Q K^T);
// att = (Q.num0k + tril(A)@Wm)/den; softmax over c; p~ = p/den;
// o = p~@num0v + tril(p~@Wm^T)@V. Writes o in (s,b,dmodel) layout.
// ---------------------------------------------------------------------------
#define PAD 68
__global__ __launch_bounds__(256) void passC(
    const float* __restrict__ qd, const float* __restrict__ kd,
    const float* __restrict__ vd, const float* __restrict__ q_c,
    const float* __restrict__ bsden, const float* __restrict__ bsnum,
    float* __restrict__ od)
{
  const int g = blockIdx.x, nb = blockIdx.y;
  const int h = g & (NH-1), b = g >> 4;
  const int s0g = nb * TS;
  const int tid = threadIdx.x;

  __shared__ float SM[18496];  // 73,984 B
#define QT(d,s)  SM[(d)*PAD + (s)]
#define VS(t,d)  SM[(t)*PAD + (d)]
#define KT(d,s)  SM[4352 + (d)*PAD + (s)]
#define ABT(t,s) SM[8704 + (t)*PAD + (s)]
#define QC(c,d)  SM[13056 + (c)*PAD + (d)]
#define PT(s,c)  SM[13056 + (s)*17 + (c)]
#define N0K(c,d) SM[14144 + (c)*PAD + (d)]
#define N0V(c,d) SM[15232 + (c)*PAD + (d)]
#define WM(t,c)  SM[16320 + (t)*17 + (c)]
#define DS(s,c)  SM[17408 + (s)*17 + (c)]

  // phase 1: stage qc, num0k/num0v, Q^T, K^T
  {
    const int c = tid >> 4, d4 = (tid & 15) * 4;
    *(float4*)&QC(c,d4) = *(const float4*)&q_c[c*DMODEL + h*DH + d4];
    const size_t nbase = (((size_t)g*NTILE + nb)*CL + c)*128;
    *(float4*)&N0K(c,d4) = *(const float4*)&bsnum[nbase + d4];
    *(float4*)&N0V(c,d4) = *(const float4*)&bsnum[nbase + 64 + d4];
  }
#pragma unroll
  for (int it = 0; it < 4; ++it) {
    const int r = (tid >> 4) + it*16, d4 = (tid & 15) * 4;
    const float4 qv = *(const float4*)&qd[((size_t)g*SEQL + s0g + r)*DH + d4];
    const float4 kv = *(const float4*)&kd[((size_t)g*SEQL + s0g + r)*DH + d4];
    QT(d4+0, r) = qv.x; QT(d4+1, r) = qv.y; QT(d4+2, r) = qv.z; QT(d4+3, r) = qv.w;
    KT(d4+0, r) = kv.x; KT(d4+1, r) = kv.y; KT(d4+2, r) = kv.z; KT(d4+3, r) = kv.w;
  }
  __syncthreads();

  // phase 2: Wm[t][c] = exp(qc[c] . k[t])
#pragma unroll
  for (int it = 0; it < 4; ++it) {
    const int item = tid + it*256;
    const int t = item & 63, c = item >> 6;
    float dot = 0.f;
    for (int d = 0; d < DH; ++d) dot += QC(c,d) * KT(d,t);
    WM(t,c) = __expf(dot);
  }
  __syncthreads();

  // phase 3a: den prefix
  {
    const size_t dbase = ((size_t)g*NTILE + nb)*CL;
#pragma unroll
    for (int it = 0; it < 4; ++it) {
      const int item = tid + it*256;
      const int s = item & 63, c = item >> 6;
      float den = bsden[dbase + c];
      for (int t = 0; t < TS; ++t) den += (t <= s) ? WM(t,c) : 0.0f;
      DS(s,c) = den;
    }
  }
  // phase 3b: A = tril(Q K^T), stored transposed ABT[t][s]
  {
    const int ts = tid >> 4, tt = tid & 15;
    const int ss = ts*4, t0 = tt*4;
    float a[4][4] = {};
    for (int d = 0; d < DH; ++d) {
      const float4 qv = *(const float4*)&QT(d, ss);
      const float4 kv = *(const float4*)&KT(d, t0);
      FMA16(a, qv, kv);
    }
#pragma unroll
    for (int i = 0; i < 4; ++i)
#pragma unroll
      for (int j = 0; j < 4; ++j)
        ABT(t0+j, ss+i) = (t0+j <= ss+i) ? a[i][j] : 0.0f;
  }
  __syncthreads();

  // phase 4: att (normalized) into PT
#pragma unroll
  for (int it = 0; it < 4; ++it) {
    const int item = tid + it*256;
    const int s = item & 63, c = item >> 6;
    float acc = 0.f;
    for (int d = 0; d < DH; ++d) acc += QT(d,s) * N0K(c,d);
    for (int t = 0; t < TS; ++t) acc += ABT(t,s) * WM(t,c);
    PT(s,c) = acc / DS(s,c);
  }
  __syncthreads();

  // phase 5: softmax over c (p~ = p/den), and stage V over Q's buffer
#pragma unroll
  for (int it = 0; it < 4; ++it) {
    const int r = (tid >> 4) + it*16, d4 = (tid & 15) * 4;
    *(float4*)&VS(r,d4) = *(const float4*)&vd[((size_t)g*SEQL + s0g + r)*DH + d4];
  }
  if (tid < TS) {
    const int s = tid;
    float m = -1e30f;
#pragma unroll
    for (int c = 0; c < CL; ++c) m = fmaxf(m, PT(s,c));
    float e[CL]; float sum = 0.f;
#pragma unroll
    for (int c = 0; c < CL; ++c) { e[c] = __expf(PT(s,c) - m); sum += e[c]; }
    const float inv = 1.0f / sum;
#pragma unroll
    for (int c = 0; c < CL; ++c) PT(s,c) = e[c] * inv / DS(s,c);
  }
  __syncthreads();

  // phase 6: B[t][s] = tril(sum_c p~[s,c] Wm[t,c]) into ABT
#pragma unroll
  for (int it = 0; it < 16; ++it) {
    const int item = tid + it*256;
    const int t = item & 63, s = item >> 6;
    float acc = 0.f;
#pragma unroll
    for (int c = 0; c < CL; ++c) acc += PT(s,c) * WM(t,c);
    ABT(t,s) = (t <= s) ? acc : 0.0f;
  }
  __syncthreads();

  // phase 7: o = p~ @ num0v + B @ V, write to (s,b,dmodel)
  {
    const int ts = tid >> 4, td = tid & 15;
    const int ss = ts*4, d0 = td*4;
    float o[4][4] = {};
#pragma unroll
    for (int c = 0; c < CL; ++c) {
      const float4 nv = *(const float4*)&N0V(c,d0);
      float4 pv;
      pv.x = PT(ss+0,c); pv.y = PT(ss+1,c); pv.z = PT(ss+2,c); pv.w = PT(ss+3,c);
      FMA16(o, pv, nv);
    }
    for (int t = 0; t < TS; ++t) {
      const float4 vv = *(const float4*)&VS(t,d0);
      const float4 bb = *(const float4*)&ABT(t,ss);
      FMA16(o, bb, vv);
    }
#pragma unroll
    for (int i = 0; i < 4; ++i) {
      const int s = s0g + ss + i;
      float4 w;
      w.x = o[i][0]; w.y = o[i][1]; w.z = o[i][2]; w.w = o[i][3];
      *(float4*)&od[((size_t)s*NBATCH + b)*DMODEL + h*DH + d0] = w;
    }
  }
}

// ---------------------------------------------------------------------------
extern "C" void kernel_launch(void* const* d_in, const int* in_sizes, int n_in,
                              void* d_out, int out_size, void* d_ws, size_t ws_size,
                              hipStream_t stream)
{
  const float* x    = (const float*)d_in[0];
  const float* q_c  = (const float*)d_in[1];
  const float* beta = (const float*)d_in[2];
  const float* Wq   = (const float*)d_in[3];
  const float* bq   = (const float*)d_in[4];
  const float* Wk   = (const float*)d_in[5];
  const float* bk   = (const float*)d_in[6];
  const float* Wv   = (const float*)d_in[7];
  const float* bv   = (const float*)d_in[8];
  const float* Wo   = (const float*)d_in[9];
  const float* bo   = (const float*)d_in[10];
  float* out = (float*)d_out;

  float* ws = (float*)d_ws;
  float* qd = ws;                               // 32*2048*64
  float* kd = qd + (size_t)G*SEQL*DH;
  float* vd = kd + (size_t)G*SEQL*DH;
  float* od = vd + (size_t)G*SEQL*DH;           // 4096*1024
  float* bsden = od + (size_t)SEQL*NBATCH*DMODEL; // 32*32*16
  float* bsnum = bsden + (size_t)G*NTILE*CL;    // 32*32*16*128

  proj_qkv<<<dim3(32, 8, 3), 256, 0, stream>>>(x, Wq, bq, Wk, bk, Wv, bv, beta, qd, kd, vd);
  passA<<<dim3(G, NTILE), 256, 0, stream>>>(kd, vd, q_c, bsden, bsnum);
  passB<<<dim3(258), 256, 0, stream>>>(bsden, bsnum);
  passC<<<dim3(G, NTILE), 256, 0, stream>>>(qd, kd, vd, q_c, bsden, bsnum, od);
  gemm_out<<<dim3(32, 8), 256, 0, stream>>>(od, Wo, bo, out);
}